// Round 13
// baseline (91.715 us; speedup 1.0000x reference)
//
#include <hip/hip_runtime.h>

#define NN 8192
#define EE 256
#define KNH 32
#define NKEEP 4096
#define NCX 64
#define NCELL 4096
#define CNT_MIN 48

typedef unsigned long long u64;
typedef unsigned int u32;

// ws layout:
// part  @ 0      [2][32][256] f32   (65536)
// gm    @ 65536  [2][256] f32       ( 2048)
// start @ 67584  [2][4097] int      (32800 alloc)
// sc    @ 100384 [2][8192] float2   (131072)
// sj    @ 231456 [2][8192] int      (65536)   -> 296992 total

__device__ __forceinline__ int cellof(float v) {
    const int q = (int)floorf((v + 4.6f) * (64.0f / 9.2f));
    return min(max(q, 0), NCX - 1);
}

// fused: blocks 0-1 = per-batch binning (count -> wave-scan -> scatter);
// blocks 2-17 = gm column-sum partials (4 units of 256 threads each).
__global__ void __launch_bounds__(1024) k_pre(const float* __restrict__ coords,
                                              const float* __restrict__ x,
                                              int* __restrict__ start,
                                              float2* __restrict__ sc,
                                              int* __restrict__ sj,
                                              float* __restrict__ part) {
    __shared__ int cnt[NCELL];
    __shared__ int wsum[16];
    const int blk = blockIdx.x;
    if (blk >= 2) {
        const int unit  = (blk - 2) * 4 + (threadIdx.x >> 8);
        const int b     = unit >> 5;
        const int chunk = unit & 31;
        const int t     = threadIdx.x & 255;
        const float* xp = x + ((size_t)b * NN + (size_t)chunk * 256) * EE + t;
        float s = 0.0f;
        for (int i = 0; i < 256; ++i) s += xp[(size_t)i * EE];
        part[((size_t)b * 32 + chunk) * EE + t] = s;
        return;
    }
    const int b = blk, t = threadIdx.x;
    const int lane = t & 63, wv = t >> 6;
#pragma unroll
    for (int k = 0; k < 4; ++k) cnt[k * 1024 + t] = 0;
    __syncthreads();
#pragma unroll
    for (int k = 0; k < 8; ++k) {
        const int i = k * 1024 + t;
        const float xv = coords[(size_t)b * 2 * NN + i];
        const float yv = coords[(size_t)b * 2 * NN + NN + i];
        atomicAdd(&cnt[cellof(xv) * NCX + cellof(yv)], 1);
    }
    __syncthreads();
    const int v0 = cnt[t * 4 + 0], v1 = cnt[t * 4 + 1];
    const int v2 = cnt[t * 4 + 2], v3 = cnt[t * 4 + 3];
    const int s = v0 + v1 + v2 + v3;
    int inc = s;
#pragma unroll
    for (int d = 1; d < 64; d <<= 1) {
        const int u = __shfl_up(inc, d);
        inc += (lane >= d) ? u : 0;
    }
    if (lane == 63) wsum[wv] = inc;
    __syncthreads();
    int wpre = 0;
#pragma unroll
    for (int w = 0; w < 16; ++w) wpre += (w < wv) ? wsum[w] : 0;
    int run = wpre + inc - s;
    start[b * (NCELL + 1) + t * 4 + 0] = run; cnt[t * 4 + 0] = run; run += v0;
    start[b * (NCELL + 1) + t * 4 + 1] = run; cnt[t * 4 + 1] = run; run += v1;
    start[b * (NCELL + 1) + t * 4 + 2] = run; cnt[t * 4 + 2] = run; run += v2;
    start[b * (NCELL + 1) + t * 4 + 3] = run; cnt[t * 4 + 3] = run; run += v3;
    if (t == 0) start[b * (NCELL + 1) + NCELL] = NN;
    __syncthreads();
#pragma unroll
    for (int k = 0; k < 8; ++k) {
        const int i = k * 1024 + t;
        const float xv = coords[(size_t)b * 2 * NN + i];
        const float yv = coords[(size_t)b * 2 * NN + NN + i];
        const int p = atomicAdd(&cnt[cellof(xv) * NCX + cellof(yv)], 1);
        sc[(size_t)b * NN + p] = make_float2(xv, yv);
        sj[(size_t)b * NN + p] = i;
    }
}

__global__ void k_gm_final(const float* __restrict__ part, float* __restrict__ gm) {
    const int b = blockIdx.y, t = threadIdx.x;
    float s = 0.0f;
    for (int c = 0; c < 32; ++c) s += part[((size_t)b * 32 + c) * EE + t];
    gm[b * EE + t] = fabsf(s / (float)NN);
}

__device__ __forceinline__ u64 shfl_xor_u64(u64 v, int m) {
    const u32 hi = (u32)__shfl_xor((int)(u32)(v >> 32), m);
    const u32 lo = (u32)__shfl_xor((int)(u32)v, m);
    return ((u64)hi << 32) | lo;
}

__device__ __forceinline__ u64 wave_min_u64(u64 h) {
#pragma unroll
    for (int s = 1; s < 64; s <<= 1) {
        const u64 o = shfl_xor_u64(h, s);
        h = (o < h) ? o : h;
    }
    return h;
}

// exact 32-round argmin over a cell box (rare certificate fallback)
__device__ __noinline__ int exact_fb(const float2* scb, const int* sjb, const int* stb,
                                     float cx, float cy, int xl, int xh, int yl, int yh,
                                     int lane) {
    const int nsl = xh - xl + 1;
    int c0 = 0, c1 = 0;
    if (lane < nsl) { c0 = stb[(xl + lane) * NCX + yl]; c1 = stb[(xl + lane) * NCX + yh + 1]; }
    const int myc = c0, len = c1 - c0;
    int inc = len;
#pragma unroll
    for (int d = 1; d < 64; d <<= 1) {
        const int v = __shfl_up(inc, d);
        inc += (lane >= d) ? v : 0;
    }
    const int ex = inc - len;
    const int L = __shfl(inc, 63);
    int jk = 0;
    u64 minkeep = 0;
    for (int k = 0; k < KNH; ++k) {
        u64 best = ~0ull;
        for (int g = 0; g < L; g += 64) {
            const int gp = g + lane;
            int lo = 0, hi = nsl - 1;
#pragma unroll
            for (int st = 0; st < 6; ++st) {
                const int mid = (lo + hi + 1) >> 1;
                const int v = __shfl(ex, mid);
                const bool go = (v <= gp);
                lo = go ? mid : lo;
                hi = go ? hi : mid - 1;
            }
            const int cnd = __shfl(myc, lo) + gp - __shfl(ex, lo);
            const int cc = min(max(cnd, 0), NN - 1);
            const float2 pt = scb[cc];
            const int jj = sjb[cc];
            const float dx = cx - pt.x, dy = cy - pt.y;
            const float d = fmaf(dx, dx, dy * dy);
            const u64 kk = ((u64)__float_as_uint(d) << 32) | (u32)jj;
            if (gp < L && kk >= minkeep && kk < best) best = kk;
        }
        const u64 h = wave_min_u64(best);
        if (lane == k) jk = (int)(u32)h;
        minkeep = h + 1;
    }
    return jk;
}

// TWO points per wave (adjacent scatter positions), fully interleaved A/B
// chains for ILP. Same per-point algorithm as the passing round-12 kernel.
__global__ void __launch_bounds__(256) k_knn_dist(
        const float* __restrict__ x,
        const float* __restrict__ gm, const float2* __restrict__ sc,
        const int* __restrict__ sj, const int* __restrict__ start,
        float* __restrict__ ld_out) {
    __shared__ u64 comp[4][2][64];
    const int wg   = blockIdx.x;              // 0..2047
    const int idx  = wg >> 3, xcd = wg & 7;
    const int swz  = (idx >> 5) * 256 + xcd * 32 + (idx & 31);   // bijective
    const int b    = swz >> 10;
    const int pb   = swz & 1023;
    const int wid  = threadIdx.x >> 6;
    const int lane = threadIdx.x & 63;
    const int pA   = (pb * 4 + wid) * 2;
    const int pB   = pA + 1;

    const float2* scb = sc + (size_t)b * NN;
    const int*    sjb = sj + (size_t)b * NN;
    const int*    stb = start + b * (NCELL + 1);
    const float2 cpA = scb[pA], cpB = scb[pB];
    const int    iA  = sjb[pA], iB = sjb[pB];
    const float ax = cpA.x, ay = cpA.y, bx = cpB.x, by = cpB.y;
    const int qxA = cellof(ax), qyA = cellof(ay);
    const int qxB = cellof(bx), qyB = cellof(by);

    // ---- adaptive squares (independent doubling, shared loop) ----
    int xlA, xhA, ylA, yhA, nslA, c0A = 0, lenA = 0, rA = 1;
    int xlB, xhB, ylB, yhB, nslB, c0B = 0, lenB = 0, rB = 1;
    bool dA = false, dB = false;
    for (;;) {
        if (!dA) {
            xlA = max(qxA - rA, 0); xhA = min(qxA + rA, NCX - 1);
            ylA = max(qyA - rA, 0); yhA = min(qyA + rA, NCX - 1);
            nslA = xhA - xlA + 1;
            int c0 = 0, c1 = 0;
            if (lane < nslA) { c0 = stb[(xlA + lane) * NCX + ylA]; c1 = stb[(xlA + lane) * NCX + yhA + 1]; }
            c0A = c0; lenA = c1 - c0;
            int tot = lenA;
#pragma unroll
            for (int s = 1; s < 64; s <<= 1) tot += __shfl_xor(tot, s);
            if (tot >= CNT_MIN || rA >= NCX) dA = true; else rA <<= 1;
        }
        if (!dB) {
            xlB = max(qxB - rB, 0); xhB = min(qxB + rB, NCX - 1);
            ylB = max(qyB - rB, 0); yhB = min(qyB + rB, NCX - 1);
            nslB = xhB - xlB + 1;
            int c0 = 0, c1 = 0;
            if (lane < nslB) { c0 = stb[(xlB + lane) * NCX + ylB]; c1 = stb[(xlB + lane) * NCX + yhB + 1]; }
            c0B = c0; lenB = c1 - c0;
            int tot = lenB;
#pragma unroll
            for (int s = 1; s < 64; s <<= 1) tot += __shfl_xor(tot, s);
            if (tot >= CNT_MIN || rB >= NCX) dB = true; else rB <<= 1;
        }
        if (dA && dB) break;
    }

    // ---- interleaved prefix scans ----
    int incA = lenA, incB = lenB;
#pragma unroll
    for (int d = 1; d < 64; d <<= 1) {
        const int vA = __shfl_up(incA, d), vB = __shfl_up(incB, d);
        incA += (lane >= d) ? vA : 0;
        incB += (lane >= d) ? vB : 0;
    }
    int exA = incA - lenA, exB = incB - lenB;
    const int L1A = __shfl(incA, 63), L1B = __shfl(incB, 63);

    // ---- pass 1: dual flattened stream, per-lane min ----
    float dmA = 1e30f, dmB = 1e30f;
    const int Lmax1 = max(L1A, L1B);
    for (int g = 0; g < Lmax1; g += 64) {
        const int gp = g + lane;
        int loA = 0, hiA = nslA - 1, loB = 0, hiB = nslB - 1;
#pragma unroll
        for (int st = 0; st < 6; ++st) {
            const int midA = (loA + hiA + 1) >> 1, midB = (loB + hiB + 1) >> 1;
            const int vA = __shfl(exA, midA), vB = __shfl(exB, midB);
            const bool goA = (vA <= gp), goB = (vB <= gp);
            loA = goA ? midA : loA; hiA = goA ? hiA : midA - 1;
            loB = goB ? midB : loB; hiB = goB ? hiB : midB - 1;
        }
        const int cndA = __shfl(c0A, loA) + gp - __shfl(exA, loA);
        const int cndB = __shfl(c0B, loB) + gp - __shfl(exB, loB);
        const int ccA = min(max(cndA, 0), NN - 1), ccB = min(max(cndB, 0), NN - 1);
        const float2 ptA = scb[ccA], ptB = scb[ccB];
        const float dxA = ax - ptA.x, dyA = ay - ptA.y;
        const float dxB = bx - ptB.x, dyB = by - ptB.y;
        const float dsA = fmaf(dxA, dxA, dyA * dyA);
        const float dsB = fmaf(dxB, dxB, dyB * dyB);
        if (gp < L1A) dmA = fminf(dmA, dsA);
        if (gp < L1B) dmB = fminf(dmB, dsB);
    }

    // ---- dual T: interleaved u32 bitonic sorts of lane minima ----
    u32 mkA = __float_as_uint(dmA), mkB = __float_as_uint(dmB);
#pragma unroll
    for (int k = 2; k <= 64; k <<= 1) {
#pragma unroll
        for (int j = k >> 1; j > 0; j >>= 1) {
            const u32 oA = (u32)__shfl_xor((int)mkA, j);
            const u32 oB = (u32)__shfl_xor((int)mkB, j);
            const bool keep = (((lane & j) == 0) == ((lane & k) == 0));
            const u32 mnA = min(mkA, oA), mxA = max(mkA, oA);
            const u32 mnB = min(mkB, oB), mxB = max(mkB, oB);
            mkA = keep ? mnA : mxA;
            mkB = keep ? mnB : mxB;
        }
    }
    const u32 TA = (u32)__shfl((int)mkA, 31);
    const u32 TB = (u32)__shfl((int)mkB, 31);

    // ---- pass-2 boxes ----
    const float srA = sqrtf(__uint_as_float(TA)) * 1.0002f + 1e-5f;
    const float srB = sqrtf(__uint_as_float(TB)) * 1.0002f + 1e-5f;
    xlA = cellof(ax - srA); xhA = cellof(ax + srA);
    ylA = cellof(ay - srA); yhA = cellof(ay + srA);
    xlB = cellof(bx - srB); xhB = cellof(bx + srB);
    ylB = cellof(by - srB); yhB = cellof(by + srB);
    nslA = xhA - xlA + 1; nslB = xhB - xlB + 1;
    {
        int c0 = 0, c1 = 0;
        if (lane < nslA) { c0 = stb[(xlA + lane) * NCX + ylA]; c1 = stb[(xlA + lane) * NCX + yhA + 1]; }
        c0A = c0; lenA = c1 - c0;
        int e0 = 0, e1 = 0;
        if (lane < nslB) { e0 = stb[(xlB + lane) * NCX + ylB]; e1 = stb[(xlB + lane) * NCX + yhB + 1]; }
        c0B = e0; lenB = e1 - e0;
    }
    incA = lenA; incB = lenB;
#pragma unroll
    for (int d = 1; d < 64; d <<= 1) {
        const int vA = __shfl_up(incA, d), vB = __shfl_up(incB, d);
        incA += (lane >= d) ? vA : 0;
        incB += (lane >= d) ? vB : 0;
    }
    exA = incA - lenA; exB = incB - lenB;
    const int L2A = __shfl(incA, 63), L2B = __shfl(incB, 63);

    // ---- pass 2: dual compact of survivors ----
    const u64 lmask = (1ull << lane) - 1;
    int baseA = 0, baseB = 0;
    const int Lmax2 = max(L2A, L2B);
    for (int g = 0; g < Lmax2; g += 64) {
        const int gp = g + lane;
        int loA = 0, hiA = nslA - 1, loB = 0, hiB = nslB - 1;
#pragma unroll
        for (int st = 0; st < 6; ++st) {
            const int midA = (loA + hiA + 1) >> 1, midB = (loB + hiB + 1) >> 1;
            const int vA = __shfl(exA, midA), vB = __shfl(exB, midB);
            const bool goA = (vA <= gp), goB = (vB <= gp);
            loA = goA ? midA : loA; hiA = goA ? hiA : midA - 1;
            loB = goB ? midB : loB; hiB = goB ? hiB : midB - 1;
        }
        const int cndA = __shfl(c0A, loA) + gp - __shfl(exA, loA);
        const int cndB = __shfl(c0B, loB) + gp - __shfl(exB, loB);
        const int ccA = min(max(cndA, 0), NN - 1), ccB = min(max(cndB, 0), NN - 1);
        const float2 ptA = scb[ccA], ptB = scb[ccB];
        const int jjA = sjb[ccA], jjB = sjb[ccB];
        const float dxA = ax - ptA.x, dyA = ay - ptA.y;
        const float dxB = bx - ptB.x, dyB = by - ptB.y;
        const u32 dbA = __float_as_uint(fmaf(dxA, dxA, dyA * dyA));
        const u32 dbB = __float_as_uint(fmaf(dxB, dxB, dyB * dyB));
        const bool kA = (gp < L2A) && (dbA <= TA);
        const bool kB = (gp < L2B) && (dbB <= TB);
        const u64 mA = __ballot(kA), mB = __ballot(kB);
        const int posA = baseA + __popcll(mA & lmask);
        const int posB = baseB + __popcll(mB & lmask);
        baseA += __popcll(mA);
        baseB += __popcll(mB);
        if (kA && posA < 64) comp[wid][0][posA] = ((u64)dbA << 32) | (u32)jjA;
        if (kB && posB < 64) comp[wid][1][posB] = ((u64)dbB << 32) | (u32)jjB;
    }
    const bool ovfA = (baseA > 64) || (baseA < KNH);
    const bool ovfB = (baseB > 64) || (baseB < KNH);

    // ---- dual u64 bitonic sort of survivors ----
    u64 keyA = (lane < baseA) ? comp[wid][0][lane] : ~0ull;
    u64 keyB = (lane < baseB) ? comp[wid][1][lane] : ~0ull;
#pragma unroll
    for (int k = 2; k <= 64; k <<= 1) {
#pragma unroll
        for (int j = k >> 1; j > 0; j >>= 1) {
            const u64 oA = shfl_xor_u64(keyA, j), oB = shfl_xor_u64(keyB, j);
            const bool keep = (((lane & j) == 0) == ((lane & k) == 0));
            const bool ltA = (keyA < oA), ltB = (keyB < oB);
            const u64 mnA = ltA ? keyA : oA, mxA = ltA ? oA : keyA;
            const u64 mnB = ltB ? keyB : oB, mxB = ltB ? oB : keyB;
            keyA = keep ? mnA : mxA;
            keyB = keep ? mnB : mxB;
        }
    }
    int jkA = (int)(u32)keyA;
    int jkB = (int)(u32)keyB;

    if (ovfA) jkA = exact_fb(scb, sjb, stb, ax, ay, xlA, xhA, ylA, yhA, lane);
    if (ovfB) jkB = exact_fb(scb, sjb, stb, bx, by, xlB, xhB, ylB, yhB, lane);

    // ---- dual gather: 32 rows each, f32 sum/sumsq (4 ch/lane) ----
    float s1A[4] = {0.f, 0.f, 0.f, 0.f}, s2A[4] = {0.f, 0.f, 0.f, 0.f};
    float s1B[4] = {0.f, 0.f, 0.f, 0.f}, s2B[4] = {0.f, 0.f, 0.f, 0.f};
    const float* xb = x + (size_t)b * NN * EE;
#pragma unroll 4
    for (int k = 0; k < KNH; ++k) {
        const int jA = __builtin_amdgcn_readlane(jkA, k);
        const int jB = __builtin_amdgcn_readlane(jkB, k);
        const float4 vA = *reinterpret_cast<const float4*>(xb + (size_t)jA * EE + (lane << 2));
        const float4 vB = *reinterpret_cast<const float4*>(xb + (size_t)jB * EE + (lane << 2));
        s1A[0] += vA.x; s2A[0] += vA.x * vA.x;
        s1B[0] += vB.x; s2B[0] += vB.x * vB.x;
        s1A[1] += vA.y; s2A[1] += vA.y * vA.y;
        s1B[1] += vB.y; s2B[1] += vB.y * vB.y;
        s1A[2] += vA.z; s2A[2] += vA.z * vA.z;
        s1B[2] += vB.z; s2B[2] += vB.z * vB.z;
        s1A[3] += vA.w; s2A[3] += vA.w * vA.w;
        s1B[3] += vB.w; s2B[3] += vB.w * vB.w;
    }

    const float* gmb = gm + b * EE;
    float ttA = 0.f, ttB = 0.f;
#pragma unroll
    for (int q = 0; q < 4; ++q) {
        const float g_ = gmb[(lane << 2) + q];
        const float suA = s1A[q], suB = s1B[q];
        float sdA = s2A[q] - suA * suA * (1.0f / 32.0f);
        float sdB = s2B[q] - suB * suB * (1.0f / 32.0f);
        sdA = sdA > 0.f ? sdA : 0.f;
        sdB = sdB > 0.f ? sdB : 0.f;
        ttA += sqrtf(sdA * (1.0f / 31.0f)) / g_;
        ttB += sqrtf(sdB * (1.0f / 31.0f)) / g_;
    }
#pragma unroll
    for (int s = 1; s < 64; s <<= 1) {
        ttA += __shfl_xor(ttA, s);
        ttB += __shfl_xor(ttB, s);
    }

    if (lane == 0) {
        ld_out[(size_t)b * NN + iA] = ttA;
        ld_out[(size_t)b * NN + iB] = ttB;
    }
}

// one wave per point: exact rank (desc, index tie-break) + direct row gather
__global__ void k_rank_gather(const float* __restrict__ x, const float* __restrict__ coords,
                              const float* __restrict__ ld,
                              float* __restrict__ x_out, float* __restrict__ c_out) {
    const int b    = blockIdx.y;
    const int wid  = threadIdx.x >> 6;
    const int lane = threadIdx.x & 63;
    const int i    = blockIdx.x * 4 + wid;
    const float* lb = ld + (size_t)b * NN;
    const float di = lb[i];
    int cnt = 0;
    for (int t = 0; t < NN / 256; ++t) {
        const int j0 = t * 256 + (lane << 2);
        const float4 dv = *reinterpret_cast<const float4*>(lb + j0);
        cnt += (dv.x > di || (dv.x == di && (j0 + 0) < i)) ? 1 : 0;
        cnt += (dv.y > di || (dv.y == di && (j0 + 1) < i)) ? 1 : 0;
        cnt += (dv.z > di || (dv.z == di && (j0 + 2) < i)) ? 1 : 0;
        cnt += (dv.w > di || (dv.w == di && (j0 + 3) < i)) ? 1 : 0;
    }
#pragma unroll
    for (int s = 1; s < 64; s <<= 1) cnt += __shfl_xor(cnt, s);

    if (cnt < NKEEP) {
        const float4 v = *reinterpret_cast<const float4*>(x + ((size_t)b * NN + i) * EE + (lane << 2));
        *reinterpret_cast<float4*>(x_out + ((size_t)b * NKEEP + cnt) * EE + (lane << 2)) = v;
        if (lane < 2) {
            c_out[((size_t)b * 2 + lane) * NKEEP + cnt] = coords[((size_t)b * 2 + lane) * NN + i];
        }
    }
}

extern "C" void kernel_launch(void* const* d_in, const int* in_sizes, int n_in,
                              void* d_out, int out_size, void* d_ws, size_t ws_size,
                              hipStream_t stream) {
    const float* x      = (const float*)d_in[0];
    const float* coords = (const float*)d_in[1];

    float* out    = (float*)d_out;
    float* x_out  = out;                 // [2][4096][256]
    float* c_out  = out + 2097152;       // [2][2][4096][1]
    float* ld_out = out + 2113536;       // [2][8192]

    char*   ws    = (char*)d_ws;
    float*  part  = (float*)(ws);
    float*  gm    = (float*)(ws + 65536);
    int*    start = (int*)  (ws + 67584);
    float2* sc    = (float2*)(ws + 100384);
    int*    sj    = (int*)  (ws + 231456);

    k_pre        <<<18,            1024, 0, stream>>>(coords, x, start, sc, sj, part);
    k_gm_final   <<<dim3(1, 2),    256,  0, stream>>>(part, gm);
    k_knn_dist   <<<2048,          256,  0, stream>>>(x, gm, sc, sj, start, ld_out);
    k_rank_gather<<<dim3(2048, 2), 256,  0, stream>>>(x, coords, ld_out, x_out, c_out);
}